// Round 1
// baseline (421.662 us; speedup 1.0000x reference)
//
#include <hip/hip_runtime.h>

// Problem: B=32, C=17, H=256, W=256 fp32.
// out = 0.5 * ( sum(m1?d:0)/sum(m1) + sum(m2?d:0)/(sum(m2)*C) )
//   m1 = target>0 per element; m2 = any(m1 over C) per (b,h,w); d = |input-target|.

#define HW_ELEMS 65536      // 256*256
#define QPB      16384      // HW/4 float4-quads per (b,c) plane
#define N_CH     17
#define N_BATCH  32
#define N_QUADS  (N_BATCH * QPB)   // 524288 pixel-quads

struct Accum {
    float s1;
    float s2;
    unsigned int c1;
    unsigned int c2;
};

__global__ void init_ws_kernel(Accum* ws) {
    ws->s1 = 0.0f;
    ws->s2 = 0.0f;
    ws->c1 = 0u;
    ws->c2 = 0u;
}

__global__ __launch_bounds__(256) void heatloss_reduce_kernel(
    const float* __restrict__ inp, const float* __restrict__ tgt,
    Accum* __restrict__ ws) {

    const float4* __restrict__ in4 = (const float4*)inp;
    const float4* __restrict__ tg4 = (const float4*)tgt;

    float s1 = 0.0f, s2 = 0.0f;
    unsigned int c1 = 0u, c2 = 0u;

    const int stride = gridDim.x * blockDim.x;
    for (int q = blockIdx.x * blockDim.x + threadIdx.x; q < N_QUADS; q += stride) {
        const int b = q >> 14;            // q / QPB
        const int r = q & (QPB - 1);      // q % QPB
        const size_t base4 = (size_t)b * N_CH * QPB + (size_t)r;

        float sa0 = 0.f, sa1 = 0.f, sa2 = 0.f, sa3 = 0.f;  // per-lane all-channel sums
        bool a0 = false, a1 = false, a2 = false, a3 = false;

        #pragma unroll
        for (int c = 0; c < N_CH; ++c) {
            const size_t off = base4 + (size_t)c * QPB;
            float4 t = tg4[off];
            float4 x = in4[off];
            float d0 = fabsf(x.x - t.x);
            float d1 = fabsf(x.y - t.y);
            float d2 = fabsf(x.z - t.z);
            float d3 = fabsf(x.w - t.w);
            sa0 += d0; sa1 += d1; sa2 += d2; sa3 += d3;
            bool p0 = t.x > 0.f, p1 = t.y > 0.f, p2 = t.z > 0.f, p3 = t.w > 0.f;
            s1 += p0 ? d0 : 0.f;  c1 += p0 ? 1u : 0u;  a0 = a0 || p0;
            s1 += p1 ? d1 : 0.f;  c1 += p1 ? 1u : 0u;  a1 = a1 || p1;
            s1 += p2 ? d2 : 0.f;  c1 += p2 ? 1u : 0u;  a2 = a2 || p2;
            s1 += p3 ? d3 : 0.f;  c1 += p3 ? 1u : 0u;  a3 = a3 || p3;
        }
        s2 += a0 ? sa0 : 0.f;  c2 += a0 ? 1u : 0u;
        s2 += a1 ? sa1 : 0.f;  c2 += a1 ? 1u : 0u;
        s2 += a2 ? sa2 : 0.f;  c2 += a2 ? 1u : 0u;
        s2 += a3 ? sa3 : 0.f;  c2 += a3 ? 1u : 0u;
    }

    // Intra-wave butterfly reduction (wave = 64 lanes on gfx950)
    #pragma unroll
    for (int off = 32; off > 0; off >>= 1) {
        s1 += __shfl_down(s1, off);
        s2 += __shfl_down(s2, off);
        c1 += __shfl_down(c1, off);
        c2 += __shfl_down(c2, off);
    }

    __shared__ float ls1[4], ls2[4];
    __shared__ unsigned int lc1[4], lc2[4];
    const int wave = threadIdx.x >> 6;
    const int lane = threadIdx.x & 63;
    if (lane == 0) {
        ls1[wave] = s1; ls2[wave] = s2;
        lc1[wave] = c1; lc2[wave] = c2;
    }
    __syncthreads();
    if (threadIdx.x == 0) {
        float S1 = ls1[0] + ls1[1] + ls1[2] + ls1[3];
        float S2 = ls2[0] + ls2[1] + ls2[2] + ls2[3];
        unsigned int C1 = lc1[0] + lc1[1] + lc1[2] + lc1[3];
        unsigned int C2 = lc2[0] + lc2[1] + lc2[2] + lc2[3];
        atomicAdd(&ws->s1, S1);
        atomicAdd(&ws->s2, S2);
        atomicAdd(&ws->c1, C1);
        atomicAdd(&ws->c2, C2);
    }
}

__global__ void finalize_kernel(const Accum* __restrict__ ws, float* __restrict__ out) {
    float mean1 = ws->s1 / (float)ws->c1;
    float mean2 = ws->s2 / ((float)ws->c2 * (float)N_CH);
    out[0] = 0.5f * (mean1 + mean2);
}

extern "C" void kernel_launch(void* const* d_in, const int* in_sizes, int n_in,
                              void* d_out, int out_size, void* d_ws, size_t ws_size,
                              hipStream_t stream) {
    const float* inp = (const float*)d_in[0];
    const float* tgt = (const float*)d_in[1];
    // d_in[2] (masks) and d_in[3] (hull) are unused by the forward pass.
    float* out = (float*)d_out;
    Accum* ws = (Accum*)d_ws;

    init_ws_kernel<<<1, 1, 0, stream>>>(ws);
    // 2048 blocks x 256 threads = 524288 threads = exactly one pixel-quad each.
    heatloss_reduce_kernel<<<2048, 256, 0, stream>>>(inp, tgt, ws);
    finalize_kernel<<<1, 1, 0, stream>>>(ws, out);
}

// Round 2
// 349.991 us; speedup vs baseline: 1.2048x; 1.2048x over previous
//
#include <hip/hip_runtime.h>

// Problem: B=32, C=17, H=256, W=256 fp32.
// out = 0.5 * ( sum(m1?d:0)/sum(m1) + sum(m2?d:0)/(sum(m2)*C) )
//   m1 = target>0 per element; m2 = any(m1 over C) per (b,h,w); d = |input-target|.

#define QPB      16384                  // (H*W)/4 float4-quads per (b,c) plane
#define N_CH     17
#define N_BATCH  32
#define N_QUADS  (N_BATCH * QPB)        // 524288 pixel-quads
#define N_BLOCKS 2048                   // N_QUADS / 256, one quad per thread

struct Slot {
    float s1;
    float s2;
    unsigned int c1;
    unsigned int c2;
};

// Stage 1: one thread = one pixel-quad; all 17 channels of target then input
// loaded into register arrays up front (34 independent global_load_dwordx4 in
// flight per wave). Per-block partials go to a PRIVATE slot — no atomics.
__global__ __launch_bounds__(256, 2) void heatloss_stage1(
    const float* __restrict__ inp, const float* __restrict__ tgt,
    Slot* __restrict__ slots) {

    const int q = blockIdx.x * 256 + threadIdx.x;   // grid sized exactly
    const int b = q >> 14;                          // q / QPB
    const int r = q & (QPB - 1);                    // q % QPB

    const float4* __restrict__ tp = (const float4*)tgt + (size_t)b * (N_CH * QPB) + r;
    const float4* __restrict__ xp = (const float4*)inp + (size_t)b * (N_CH * QPB) + r;

    float4 t[N_CH];
    float4 x[N_CH];
    #pragma unroll
    for (int c = 0; c < N_CH; ++c) t[c] = tp[(size_t)c * QPB];
    #pragma unroll
    for (int c = 0; c < N_CH; ++c) x[c] = xp[(size_t)c * QPB];

    float s1 = 0.0f;
    unsigned int c1 = 0u;
    float sa0 = 0.f, sa1 = 0.f, sa2 = 0.f, sa3 = 0.f;
    bool a0 = false, a1 = false, a2 = false, a3 = false;

    #pragma unroll
    for (int c = 0; c < N_CH; ++c) {
        float d0 = fabsf(x[c].x - t[c].x);
        float d1 = fabsf(x[c].y - t[c].y);
        float d2 = fabsf(x[c].z - t[c].z);
        float d3 = fabsf(x[c].w - t[c].w);
        bool p0 = t[c].x > 0.f, p1 = t[c].y > 0.f, p2 = t[c].z > 0.f, p3 = t[c].w > 0.f;
        sa0 += d0; sa1 += d1; sa2 += d2; sa3 += d3;
        s1 += p0 ? d0 : 0.f;  c1 += p0 ? 1u : 0u;  a0 = a0 || p0;
        s1 += p1 ? d1 : 0.f;  c1 += p1 ? 1u : 0u;  a1 = a1 || p1;
        s1 += p2 ? d2 : 0.f;  c1 += p2 ? 1u : 0u;  a2 = a2 || p2;
        s1 += p3 ? d3 : 0.f;  c1 += p3 ? 1u : 0u;  a3 = a3 || p3;
    }
    float s2 = (a0 ? sa0 : 0.f) + (a1 ? sa1 : 0.f) + (a2 ? sa2 : 0.f) + (a3 ? sa3 : 0.f);
    unsigned int c2 = (a0 ? 1u : 0u) + (a1 ? 1u : 0u) + (a2 ? 1u : 0u) + (a3 ? 1u : 0u);

    // Intra-wave butterfly reduction (wave = 64 on gfx950)
    #pragma unroll
    for (int off = 32; off > 0; off >>= 1) {
        s1 += __shfl_down(s1, off);
        s2 += __shfl_down(s2, off);
        c1 += __shfl_down(c1, off);
        c2 += __shfl_down(c2, off);
    }

    __shared__ float ls1[4], ls2[4];
    __shared__ unsigned int lc1[4], lc2[4];
    const int wave = threadIdx.x >> 6;
    const int lane = threadIdx.x & 63;
    if (lane == 0) {
        ls1[wave] = s1; ls2[wave] = s2;
        lc1[wave] = c1; lc2[wave] = c2;
    }
    __syncthreads();
    if (threadIdx.x == 0) {
        Slot sl;
        sl.s1 = ls1[0] + ls1[1] + ls1[2] + ls1[3];
        sl.s2 = ls2[0] + ls2[1] + ls2[2] + ls2[3];
        sl.c1 = lc1[0] + lc1[1] + lc1[2] + lc1[3];
        sl.c2 = lc2[0] + lc2[1] + lc2[2] + lc2[3];
        slots[blockIdx.x] = sl;   // private slot — no contention
    }
}

// Stage 2: one block sums the 2048 per-block slots (counts summed exactly as
// uints) and writes the final scalar.
__global__ __launch_bounds__(256) void heatloss_stage2(
    const Slot* __restrict__ slots, float* __restrict__ out) {

    float s1 = 0.f, s2 = 0.f;
    unsigned int c1 = 0u, c2 = 0u;
    for (int i = threadIdx.x; i < N_BLOCKS; i += 256) {
        Slot sl = slots[i];
        s1 += sl.s1; s2 += sl.s2; c1 += sl.c1; c2 += sl.c2;
    }
    #pragma unroll
    for (int off = 32; off > 0; off >>= 1) {
        s1 += __shfl_down(s1, off);
        s2 += __shfl_down(s2, off);
        c1 += __shfl_down(c1, off);
        c2 += __shfl_down(c2, off);
    }
    __shared__ float ls1[4], ls2[4];
    __shared__ unsigned int lc1[4], lc2[4];
    const int wave = threadIdx.x >> 6;
    const int lane = threadIdx.x & 63;
    if (lane == 0) {
        ls1[wave] = s1; ls2[wave] = s2;
        lc1[wave] = c1; lc2[wave] = c2;
    }
    __syncthreads();
    if (threadIdx.x == 0) {
        float S1 = ls1[0] + ls1[1] + ls1[2] + ls1[3];
        float S2 = ls2[0] + ls2[1] + ls2[2] + ls2[3];
        float C1 = (float)(lc1[0] + lc1[1] + lc1[2] + lc1[3]);
        float C2 = (float)(lc2[0] + lc2[1] + lc2[2] + lc2[3]);
        float mean1 = S1 / C1;
        float mean2 = S2 / (C2 * (float)N_CH);
        out[0] = 0.5f * (mean1 + mean2);
    }
}

extern "C" void kernel_launch(void* const* d_in, const int* in_sizes, int n_in,
                              void* d_out, int out_size, void* d_ws, size_t ws_size,
                              hipStream_t stream) {
    const float* inp = (const float*)d_in[0];
    const float* tgt = (const float*)d_in[1];
    // d_in[2] (masks) and d_in[3] (hull) are unused by the forward pass.
    float* out = (float*)d_out;
    Slot* slots = (Slot*)d_ws;   // 2048 * 16 B = 32 KB scratch

    heatloss_stage1<<<N_BLOCKS, 256, 0, stream>>>(inp, tgt, slots);
    heatloss_stage2<<<1, 256, 0, stream>>>(slots, out);
}

// Round 3
// 346.895 us; speedup vs baseline: 1.2155x; 1.0089x over previous
//
#include <hip/hip_runtime.h>

// Problem: B=32, C=17, H=256, W=256 fp32.
// out = 0.5 * ( sum(m1?d:0)/sum(m1) + sum(m2?d:0)/(sum(m2)*C) )
//   m1 = target>0 per element; m2 = any(m1 over C) per (b,h,w); d = |input-target|.

#define QPB      16384                  // (H*W)/4 float4-quads per (b,c) plane
#define N_CH     17
#define N_BATCH  32
#define N_QUADS  (N_BATCH * QPB)        // 524288 pixel-quads
#define N_BLOCKS 2048                   // one quad per thread
#define PF       3                      // channel-pair prefetch depth (6 loads in flight)

struct Slot {
    float s1;
    float s2;
    unsigned int c1;
    unsigned int c2;
};

// Stage 1: one thread = one pixel-quad; 17 channels processed through a
// depth-3 software-pipelined ring (t,x pairs) so ~6 global_load_dwordx4 stay
// in flight per wave at VGPR<=64 (8 waves/SIMD pinned via launch_bounds).
__global__ __launch_bounds__(256, 8) void heatloss_stage1(
    const float* __restrict__ inp, const float* __restrict__ tgt,
    Slot* __restrict__ slots) {

    // Blocks are assigned to XCDs round-robin (xcd = blockIdx % 8). Remap so
    // each XCD sweeps one contiguous range of q — L3/DRAM-channel locality.
    const int blk = (blockIdx.x & 7) * (N_BLOCKS / 8) + (blockIdx.x >> 3);
    const int q = blk * 256 + threadIdx.x;
    const int b = q >> 14;                          // q / QPB
    const int r = q & (QPB - 1);                    // q % QPB

    const float4* __restrict__ tp = (const float4*)tgt + (size_t)b * (N_CH * QPB) + r;
    const float4* __restrict__ xp = (const float4*)inp + (size_t)b * (N_CH * QPB) + r;

    float4 tb[PF], xb[PF];
    #pragma unroll
    for (int i = 0; i < PF; ++i) {
        tb[i] = tp[(size_t)i * QPB];
        xb[i] = xp[(size_t)i * QPB];
    }

    float s1 = 0.0f;
    unsigned int c1 = 0u;
    float sa0 = 0.f, sa1 = 0.f, sa2 = 0.f, sa3 = 0.f;
    bool a0 = false, a1 = false, a2 = false, a3 = false;

    #pragma unroll
    for (int c = 0; c < N_CH; ++c) {
        const int slot = c % PF;
        float4 t = tb[slot];
        float4 x = xb[slot];
        if (c + PF < N_CH) {                         // refill ring slot
            tb[slot] = tp[(size_t)(c + PF) * QPB];
            xb[slot] = xp[(size_t)(c + PF) * QPB];
        }
        float d0 = fabsf(x.x - t.x);
        float d1 = fabsf(x.y - t.y);
        float d2 = fabsf(x.z - t.z);
        float d3 = fabsf(x.w - t.w);
        bool p0 = t.x > 0.f, p1 = t.y > 0.f, p2 = t.z > 0.f, p3 = t.w > 0.f;
        sa0 += d0; sa1 += d1; sa2 += d2; sa3 += d3;
        s1 += p0 ? d0 : 0.f;  c1 += p0 ? 1u : 0u;  a0 = a0 || p0;
        s1 += p1 ? d1 : 0.f;  c1 += p1 ? 1u : 0u;  a1 = a1 || p1;
        s1 += p2 ? d2 : 0.f;  c1 += p2 ? 1u : 0u;  a2 = a2 || p2;
        s1 += p3 ? d3 : 0.f;  c1 += p3 ? 1u : 0u;  a3 = a3 || p3;
    }
    float s2 = (a0 ? sa0 : 0.f) + (a1 ? sa1 : 0.f) + (a2 ? sa2 : 0.f) + (a3 ? sa3 : 0.f);
    unsigned int c2 = (a0 ? 1u : 0u) + (a1 ? 1u : 0u) + (a2 ? 1u : 0u) + (a3 ? 1u : 0u);

    // Intra-wave butterfly reduction (wave = 64 on gfx950)
    #pragma unroll
    for (int off = 32; off > 0; off >>= 1) {
        s1 += __shfl_down(s1, off);
        s2 += __shfl_down(s2, off);
        c1 += __shfl_down(c1, off);
        c2 += __shfl_down(c2, off);
    }

    __shared__ float ls1[4], ls2[4];
    __shared__ unsigned int lc1[4], lc2[4];
    const int wave = threadIdx.x >> 6;
    const int lane = threadIdx.x & 63;
    if (lane == 0) {
        ls1[wave] = s1; ls2[wave] = s2;
        lc1[wave] = c1; lc2[wave] = c2;
    }
    __syncthreads();
    if (threadIdx.x == 0) {
        Slot sl;
        sl.s1 = ls1[0] + ls1[1] + ls1[2] + ls1[3];
        sl.s2 = ls2[0] + ls2[1] + ls2[2] + ls2[3];
        sl.c1 = lc1[0] + lc1[1] + lc1[2] + lc1[3];
        sl.c2 = lc2[0] + lc2[1] + lc2[2] + lc2[3];
        slots[blockIdx.x] = sl;   // private slot — no contention
    }
}

// Stage 2: one block sums the 2048 per-block slots (counts summed exactly as
// uints) and writes the final scalar.
__global__ __launch_bounds__(256) void heatloss_stage2(
    const Slot* __restrict__ slots, float* __restrict__ out) {

    float s1 = 0.f, s2 = 0.f;
    unsigned int c1 = 0u, c2 = 0u;
    for (int i = threadIdx.x; i < N_BLOCKS; i += 256) {
        Slot sl = slots[i];
        s1 += sl.s1; s2 += sl.s2; c1 += sl.c1; c2 += sl.c2;
    }
    #pragma unroll
    for (int off = 32; off > 0; off >>= 1) {
        s1 += __shfl_down(s1, off);
        s2 += __shfl_down(s2, off);
        c1 += __shfl_down(c1, off);
        c2 += __shfl_down(c2, off);
    }
    __shared__ float ls1[4], ls2[4];
    __shared__ unsigned int lc1[4], lc2[4];
    const int wave = threadIdx.x >> 6;
    const int lane = threadIdx.x & 63;
    if (lane == 0) {
        ls1[wave] = s1; ls2[wave] = s2;
        lc1[wave] = c1; lc2[wave] = c2;
    }
    __syncthreads();
    if (threadIdx.x == 0) {
        float S1 = ls1[0] + ls1[1] + ls1[2] + ls1[3];
        float S2 = ls2[0] + ls2[1] + ls2[2] + ls2[3];
        float C1 = (float)(lc1[0] + lc1[1] + lc1[2] + lc1[3]);
        float C2 = (float)(lc2[0] + lc2[1] + lc2[2] + lc2[3]);
        float mean1 = S1 / C1;
        float mean2 = S2 / (C2 * (float)N_CH);
        out[0] = 0.5f * (mean1 + mean2);
    }
}

extern "C" void kernel_launch(void* const* d_in, const int* in_sizes, int n_in,
                              void* d_out, int out_size, void* d_ws, size_t ws_size,
                              hipStream_t stream) {
    const float* inp = (const float*)d_in[0];
    const float* tgt = (const float*)d_in[1];
    // d_in[2] (masks) and d_in[3] (hull) are unused by the forward pass.
    float* out = (float*)d_out;
    Slot* slots = (Slot*)d_ws;   // 2048 * 16 B = 32 KB scratch

    heatloss_stage1<<<N_BLOCKS, 256, 0, stream>>>(inp, tgt, slots);
    heatloss_stage2<<<1, 256, 0, stream>>>(slots, out);
}